// Round 8
// baseline (18.263 us; speedup 1.0000x reference)
//
#include <hip/hip_runtime.h>
#include <hip/hip_bf16.h>
#include <math.h>

#define NB    512
#define DXN   100
#define MROW  128
#define TC    130
#define G     16     // rows per block
#define CB    256    // cols per block (half of NB) -> 2 blocks/CU
#define BT    512
#define KP    128    // padded K
#define AP    132    // LDS row stride (shorts): stride 264 B -> bank step 2 (free)
#define T0f   (-5.0f)
#define Hf    (10.0f / 99.0f)
#define LOG2E 1.4426950408889634f
#define WLO   42     // K-active t-window start; s_f covers t in [42, 74)

typedef __attribute__((ext_vector_type(8))) short  short8;
typedef __attribute__((ext_vector_type(4))) float  f32x4;

__device__ __forceinline__ float Tval(int t) { return T0f + Hf * (float)t; }

__device__ __forceinline__ unsigned short f2bf(float x) {
    __hip_bfloat16 b = __float2bfloat16(x);
    unsigned short u; __builtin_memcpy(&u, &b, 2); return u;
}
__device__ __forceinline__ float bf2f(unsigned short h) {
    return __uint_as_float(((unsigned)h) << 16);
}
__device__ __forceinline__ unsigned pk2bf(float lo, float hi) {
    __hip_bfloat162 b2 = __float22bfloat162_rn(float2{lo, hi});
    unsigned u; __builtin_memcpy(&u, &b2, 4); return u;
}

// ONE kernel, 512 blocks x 512 threads (2 blocks/CU). Block = 16 rows x 256 cols.
// colslab = bid>>8 so the two col-halves of a row-slab share an XCD (theta L2 reuse).
// dw hi/lo LDS overlays the dead alpha hi/lo region -> 78.3 KB/block.
__global__ __launch_bounds__(BT, 4) void fused_kernel(
    const float* __restrict__ theta,
    const float* __restrict__ mu,
    const float* __restrict__ sigma,
    float* __restrict__ out, int Bn)
{
    __shared__ __align__(16) unsigned short sB[CB * AP];     // 67584 B
    __shared__ __align__(16) unsigned short sU[2 * G * AP];  // union: alpha hi/lo, then dw hi/lo (8448 B)
    __shared__ float s_f[G * 32];                            // 2048 B
    __shared__ __align__(16) float s_muc[G];
    __shared__ __align__(16) float s_negth1[G];
    __shared__ __align__(16) float s_invZ[G];                // total ~78.3 KB

    unsigned short* sAlH = sU;                 // alpha hi   (phases 1-2b)
    unsigned short* sAlL = sU + G * AP;        // alpha lo
    unsigned short* sAh  = sU;                 // dw hi      (phases 3+)
    unsigned short* sAl  = sU + G * AP;        // dw lo

    const int tid  = threadIdx.x;
    const int bid  = blockIdx.x;
    const int b0   = (bid & 255) * G;          // row slab
    const int c0   = (bid >> 8) * CB;          // col half
    const int lane = tid & 63;
    const int wv   = tid >> 6;
    const int lrow = lane & 15;
    const int kg   = (lane >> 4) * 8;

    // ---- issue all global loads up front ----
    const int   pcol  = tid >> 1;              // 0..255 (2 threads per col)
    const int   khalf = tid & 1;               // k-half 0..63 / 64..127
    const float mun = mu[c0 + pcol];
    const float sgn = sigma[c0 + pcol];
    float tv[5];
    #pragma unroll
    for (int k = 0; k < 5; ++k) {
        int i = tid + k * BT;
        int r = i / TC, c = i - r * TC;
        int br = b0 + r; if (br >= Bn) br = Bn - 1;
        tv[k] = (i < G * TC) ? theta[br * TC + c] : 0.0f;
    }

    // ---- Phase 0: B = phi bf16 [col][k], this thread does 64 k's (4 segs of 16) ----
    {
        const float inv_s = 1.0f / sgn;
        const float dlt = Hf * inv_s;
        const float Lh  = 0.5f * LOG2E;
        const float cc  = -2.0f * Lh * dlt * dlt;
        const float S   = __log2f(0.3989422804014327f * inv_s);
        unsigned short* myB = &sB[pcol * AP + khalf * 64];
        #pragma unroll
        for (int s = 0; s < 4; ++s) {
            const int k0 = khalf * 64 + s * 16;
            if (k0 >= DXN + 12) {                          // k0 == 112: all pad
                *(uint4*)&myB[s * 16]     = make_uint4(0u, 0u, 0u, 0u);
                *(uint4*)&myB[s * 16 + 8] = make_uint4(0u, 0u, 0u, 0u);
            } else {
                float u  = (mun - Tval(k0)) * inv_s;
                float a  = S - Lh * u * u;
                float bb = Lh * dlt * (2.0f * u - dlt);
                unsigned w[8];
                #pragma unroll
                for (int j = 0; j < 8; ++j) {
                    int k = k0 + 2 * j;
                    float p0 = __builtin_amdgcn_exp2f(a); a += bb; bb += cc;
                    float p1 = __builtin_amdgcn_exp2f(a); a += bb; bb += cc;
                    if (k     >= DXN) p0 = 0.0f;
                    if (k + 1 >= DXN) p1 = 0.0f;
                    w[j] = pk2bf(p0, p1);
                }
                *(uint4*)&myB[s * 16]     = make_uint4(w[0], w[1], w[2], w[3]);
                *(uint4*)&myB[s * 16 + 8] = make_uint4(w[4], w[5], w[6], w[7]);
            }
        }
    }

    // ---- Phase 1: theta -> alpha bf16 hi/lo + raw th0/th1 ----
    #pragma unroll
    for (int k = 0; k < 5; ++k) {
        int i = tid + k * BT;
        if (i < G * TC) {
            int r = i / TC, c = i - r * TC;
            float v = tv[k];
            if (c >= 2) {
                unsigned short h = f2bf(v);
                sAlH[r * AP + (c - 2)] = h;
                sAlL[r * AP + (c - 2)] = f2bf(v - bf2f(h));
            } else if (c == 0) s_muc[r] = v;
            else               s_negth1[r] = v;
        }
    }
    __syncthreads();

    // ---- Phase 2a: per-row scalars ----
    if (tid < G) {
        float th1 = s_negth1[tid];             // <= -0.5
        s_muc[tid]    = s_muc[tid] * (-0.5f / th1);
        s_negth1[tid] = -th1;
    }

    // ---- Phase 2b: f = alpha @ K via MFMA; waves 0,1; K-frags in registers ----
    if (wv < 2) {
        const int tcol = WLO + wv * 16 + lrow;
        const float T  = Tval(tcol);
        const float C2 = 50.0f * LOG2E;
        const float dj = 1.0f / 127.0f;
        f32x4 fa = {0.0f, 0.0f, 0.0f, 0.0f};
        #pragma unroll
        for (int ks = 0; ks < 4; ++ks) {
            short8 ah = *(const short8*)&sAlH[lrow * AP + ks * 32 + kg];
            short8 al = *(const short8*)&sAlL[lrow * AP + ks * 32 + kg];
            short8 kh, kl;
            #pragma unroll
            for (int jj = 0; jj < 8; ++jj) {
                float d  = (float)(ks * 32 + kg + jj) * dj - T;
                float kv = __builtin_amdgcn_exp2f(-C2 * d * d);
                unsigned short h = f2bf(kv);
                kh[jj] = (short)h;
                kl[jj] = (short)f2bf(kv - bf2f(h));
            }
            fa = __builtin_amdgcn_mfma_f32_16x16x32_bf16(ah, kh, fa, 0, 0, 0);
            fa = __builtin_amdgcn_mfma_f32_16x16x32_bf16(al, kh, fa, 0, 0, 0);
            fa = __builtin_amdgcn_mfma_f32_16x16x32_bf16(ah, kl, fa, 0, 0, 0);
        }
        #pragma unroll
        for (int j = 0; j < 4; ++j)
            s_f[((lane >> 4) * 4 + j) * 32 + wv * 16 + lrow] = fa[j];
    }
    __syncthreads();

    // ---- Phase 3: dw -> A bf16 hi/lo (overwrites alpha region). Wave wv, round rd
    //      owns row rd*8+wv; lane handles t = 2*lane, 2*lane+1 ----
    #pragma unroll
    for (int rd = 0; rd < 2; ++rd) {
        const int row = rd * 8 + wv;
        const float muc = s_muc[row], nth = s_negth1[row];
        const int t0 = 2 * lane;
        float dw0 = 0.0f, dw1 = 0.0f;
        if (t0 < DXN) {
            unsigned i0 = (unsigned)(t0 - WLO);
            float f0 = (i0 < 32u) ? s_f[row * 32 + i0] : 0.0f;
            float dm0 = muc - Tval(t0);
            float e0 = fmaxf(1.0f + f0 - nth * dm0 * dm0, 1e-8f);
            dw0 = e0 * ((t0 == 0) ? Hf * 0.5f : Hf);
            const int t1 = t0 + 1;
            unsigned i1 = (unsigned)(t1 - WLO);
            float f1 = (i1 < 32u) ? s_f[row * 32 + i1] : 0.0f;
            float dm1 = muc - Tval(t1);
            float e1 = fmaxf(1.0f + f1 - nth * dm1 * dm1, 1e-8f);
            dw1 = e1 * ((t1 == DXN - 1) ? Hf * 0.5f : Hf);
        }
        unsigned short h0 = f2bf(dw0), h1 = f2bf(dw1);
        unsigned short l0 = f2bf(dw0 - bf2f(h0)), l1 = f2bf(dw1 - bf2f(h1));
        ((unsigned*)sAh)[row * (AP / 2) + lane] = ((unsigned)h1 << 16) | h0;
        ((unsigned*)sAl)[row * (AP / 2) + lane] = ((unsigned)l1 << 16) | l0;
    }
    __syncthreads();

    // ---- Phase 4: MFMA GEMM (2 col-tiles/wave) + Z via ones-MFMA on wave 0 ----
    short8 Ah[4], Al[4];
    #pragma unroll
    for (int ks = 0; ks < 4; ++ks) {
        Ah[ks] = *(const short8*)&sAh[lrow * AP + ks * 32 + kg];
        Al[ks] = *(const short8*)&sAl[lrow * AP + ks * 32 + kg];
    }
    f32x4 acc[2];
    #pragma unroll
    for (int ct = 0; ct < 2; ++ct) {
        const int n = wv * 32 + ct * 16 + lrow;
        f32x4 a = {0.0f, 0.0f, 0.0f, 0.0f};
        #pragma unroll
        for (int ks = 0; ks < 4; ++ks) {
            short8 b = *(const short8*)&sB[n * AP + ks * 32 + kg];
            a = __builtin_amdgcn_mfma_f32_16x16x32_bf16(Ah[ks], b, a, 0, 0, 0);
            a = __builtin_amdgcn_mfma_f32_16x16x32_bf16(Al[ks], b, a, 0, 0, 0);
        }
        acc[ct] = a;
    }
    if (wv == 0) {
        short8 ones;
        #pragma unroll
        for (int jj = 0; jj < 8; ++jj) ones[jj] = (short)0x3F80;   // bf16 1.0
        f32x4 az = {0.0f, 0.0f, 0.0f, 0.0f};
        #pragma unroll
        for (int ks = 0; ks < 4; ++ks) {
            az = __builtin_amdgcn_mfma_f32_16x16x32_bf16(Ah[ks], ones, az, 0, 0, 0);
            az = __builtin_amdgcn_mfma_f32_16x16x32_bf16(Al[ks], ones, az, 0, 0, 0);
        }
        if ((lane & 15) == 0) {
            #pragma unroll
            for (int j = 0; j < 4; ++j)
                s_invZ[(lane >> 4) * 4 + j] = 1.0f / az[j];
        }
    }
    __syncthreads();

    // ---- Epilogue: out = acc * invZ ----
    f32x4 iz = *(const f32x4*)&s_invZ[(lane >> 4) * 4];
    #pragma unroll
    for (int ct = 0; ct < 2; ++ct) {
        int col = c0 + wv * 32 + ct * 16 + lrow;
        #pragma unroll
        for (int j = 0; j < 4; ++j) {
            int row = b0 + (lane >> 4) * 4 + j;
            if (row < Bn) out[row * NB + col] = acc[ct][j] * iz[j];
        }
    }
}

extern "C" void kernel_launch(void* const* d_in, const int* in_sizes, int n_in,
                              void* d_out, int out_size, void* d_ws, size_t ws_size,
                              hipStream_t stream) {
    const float* theta = (const float*)d_in[0];
    const float* mu    = (const float*)d_in[1];
    const float* sigma = (const float*)d_in[2];
    float* outp = (float*)d_out;

    int Bn = in_sizes[0] / TC;                       // 4096
    int grid = ((Bn + G - 1) / G) * 2;               // 256 rowslabs x 2 colslabs = 512
    fused_kernel<<<grid, BT, 0, stream>>>(theta, mu, sigma, outp, Bn);
}

// Round 9
// 15.021 us; speedup vs baseline: 1.2158x; 1.2158x over previous
//
#include <hip/hip_runtime.h>
#include <hip/hip_bf16.h>
#include <math.h>

#define NB    512
#define DXN   100
#define MROW  128
#define TC    130
#define G     16     // rows per block
#define BT    512
#define AP    132    // LDS row stride (shorts)
#define T0f   (-5.0f)
#define Hf    (10.0f / 99.0f)
#define LOG2E 1.4426950408889634f
#define LHALF 0.7213475204444817f    // 0.5 * LOG2E
#define L2PHI (-1.3257480647361593f) // log2(1/sqrt(2*pi))
#define WLO   42     // K-active t-window start; s_f covers t in [42, 74)

typedef __attribute__((ext_vector_type(8))) short  short8;
typedef __attribute__((ext_vector_type(4))) float  f32x4;

__device__ __forceinline__ float Tval(int t) { return T0f + Hf * (float)t; }

__device__ __forceinline__ unsigned short f2bf(float x) {
    __hip_bfloat16 b = __float2bfloat16(x);
    unsigned short u; __builtin_memcpy(&u, &b, 2); return u;
}
__device__ __forceinline__ float bf2f(unsigned short h) {
    return __uint_as_float(((unsigned)h) << 16);
}

// ONE kernel, 256 blocks x 512 threads (1 block/CU). Block = 16 rows x 512 cols.
// B (phi) is never materialized in LDS: each wave JITs its B-fragments in
// registers (waves 2-7 pre-cache ct=0,1 during the f-MFMA window). Z is a
// per-wave ones-MFMA (az[j] == Z of this lane's epilogue rows). 3 barriers.
__global__ __launch_bounds__(BT) void fused_kernel(
    const float* __restrict__ theta,
    const float* __restrict__ mu,
    const float* __restrict__ sigma,
    float* __restrict__ out, int Bn)
{
    __shared__ __align__(16) unsigned short sAlH[G * AP];   // alpha hi
    __shared__ __align__(16) unsigned short sAlL[G * AP];   // alpha lo
    __shared__ __align__(16) unsigned short sDwH[G * AP];   // dw hi
    __shared__ __align__(16) unsigned short sDwL[G * AP];   // dw lo
    __shared__ float s_f[G * 32];
    __shared__ __align__(16) float s_muc[G];
    __shared__ __align__(16) float s_negth1[G];             // ~36 KB total

    const int tid  = threadIdx.x;
    const int b0   = blockIdx.x * G;
    const int lane = tid & 63;
    const int wv   = tid >> 6;
    const int lrow = lane & 15;
    const int kg   = (lane >> 4) * 8;
    const float kgf = (float)kg;

    // ---- issue all global loads up front ----
    float mun4[4], is4[4], S4[4];
    #pragma unroll
    for (int ct = 0; ct < 4; ++ct) {
        const int n = wv * 64 + ct * 16 + lrow;
        float m = mu[n], s = sigma[n];
        mun4[ct] = m;
        is4[ct]  = __builtin_amdgcn_rcpf(s);
        S4[ct]   = L2PHI - __log2f(s);
    }
    float tv[5];
    #pragma unroll
    for (int k = 0; k < 5; ++k) {
        int i = tid + k * BT;
        int r = i / TC, c = i - r * TC;
        int br = b0 + r; if (br >= Bn) br = Bn - 1;
        tv[k] = (i < G * TC) ? theta[br * TC + c] : 0.0f;
    }

    // ---- Phase 1: theta -> alpha bf16 hi/lo + raw th0/th1 ----
    #pragma unroll
    for (int k = 0; k < 5; ++k) {
        int i = tid + k * BT;
        if (i < G * TC) {
            int r = i / TC, c = i - r * TC;
            float v = tv[k];
            if (c >= 2) {
                unsigned short h = f2bf(v);
                sAlH[r * AP + (c - 2)] = h;
                sAlL[r * AP + (c - 2)] = f2bf(v - bf2f(h));
            } else if (c == 0) s_muc[r] = v;
            else               s_negth1[r] = v;
        }
    }
    __syncthreads();   // B1

    // ---- Phase 2: wave 0 scalars; waves 0-1 f-MFMA; waves 2-7 cache B ct=0,1 ----
    if (tid < G) {
        float th1 = s_negth1[tid];            // <= -0.5
        s_muc[tid]    = s_muc[tid] * (-0.5f / th1);
        s_negth1[tid] = -th1;
    }
    short8 bc[2][4];   // cached B frags (ct=0,1) for waves 2-7
    if (wv < 2) {
        const int tcol = WLO + wv * 16 + lrow;
        const float T  = Tval(tcol);
        const float C2 = 50.0f * LOG2E;
        const float dj = 1.0f / 127.0f;
        f32x4 fa = {0.0f, 0.0f, 0.0f, 0.0f};
        #pragma unroll
        for (int ks = 0; ks < 4; ++ks) {
            short8 ah = *(const short8*)&sAlH[lrow * AP + ks * 32 + kg];
            short8 al = *(const short8*)&sAlL[lrow * AP + ks * 32 + kg];
            short8 kh, kl;
            #pragma unroll
            for (int jj = 0; jj < 8; ++jj) {
                float d  = (float)(ks * 32 + kg + jj) * dj - T;
                float kv = __builtin_amdgcn_exp2f(-C2 * d * d);
                unsigned short h = f2bf(kv);
                kh[jj] = (short)h;
                kl[jj] = (short)f2bf(kv - bf2f(h));
            }
            fa = __builtin_amdgcn_mfma_f32_16x16x32_bf16(ah, kh, fa, 0, 0, 0);
            fa = __builtin_amdgcn_mfma_f32_16x16x32_bf16(al, kh, fa, 0, 0, 0);
            fa = __builtin_amdgcn_mfma_f32_16x16x32_bf16(ah, kl, fa, 0, 0, 0);
        }
        #pragma unroll
        for (int j = 0; j < 4; ++j)
            s_f[((lane >> 4) * 4 + j) * 32 + wv * 16 + lrow] = fa[j];
    } else {
        #pragma unroll
        for (int ct = 0; ct < 2; ++ct) {
            #pragma unroll
            for (int ks = 0; ks < 4; ++ks) {
                #pragma unroll
                for (int jj = 0; jj < 8; ++jj) {
                    int k = ks * 32 + kg + jj;
                    float u = (mun4[ct] - (T0f + Hf * (float)k)) * is4[ct];
                    float p = __builtin_amdgcn_exp2f(__builtin_fmaf(-LHALF * u, u, S4[ct]));
                    if (k >= DXN) p = 0.0f;
                    bc[ct][ks][jj] = (short)f2bf(p);
                }
            }
        }
    }
    __syncthreads();   // B2 (s_f + scalars ready)

    // ---- Phase 3: dw -> bf16 hi/lo. Wave wv, round rd owns row rd*8+wv;
    //      lane handles t = 2*lane, 2*lane+1 ----
    #pragma unroll
    for (int rd = 0; rd < 2; ++rd) {
        const int row = rd * 8 + wv;
        const float muc = s_muc[row], nth = s_negth1[row];
        const int t0 = 2 * lane;
        float dw0 = 0.0f, dw1 = 0.0f;
        if (t0 < DXN) {
            unsigned i0 = (unsigned)(t0 - WLO);
            float f0 = (i0 < 32u) ? s_f[row * 32 + i0] : 0.0f;
            float dm0 = muc - Tval(t0);
            float e0 = fmaxf(1.0f + f0 - nth * dm0 * dm0, 1e-8f);
            dw0 = e0 * ((t0 == 0) ? Hf * 0.5f : Hf);
            const int t1 = t0 + 1;
            unsigned i1 = (unsigned)(t1 - WLO);
            float f1 = (i1 < 32u) ? s_f[row * 32 + i1] : 0.0f;
            float dm1 = muc - Tval(t1);
            float e1 = fmaxf(1.0f + f1 - nth * dm1 * dm1, 1e-8f);
            dw1 = e1 * ((t1 == DXN - 1) ? Hf * 0.5f : Hf);
        }
        unsigned short h0 = f2bf(dw0), h1 = f2bf(dw1);
        unsigned short l0 = f2bf(dw0 - bf2f(h0)), l1 = f2bf(dw1 - bf2f(h1));
        ((unsigned*)sDwH)[row * (AP / 2) + lane] = ((unsigned)h1 << 16) | h0;
        ((unsigned*)sDwL)[row * (AP / 2) + lane] = ((unsigned)l1 << 16) | l0;
    }
    __syncthreads();   // B3

    // ---- Phase 4: A-frags, GEMM with JIT/cached B, per-wave Z, epilogue ----
    short8 Ah[4], Al[4];
    #pragma unroll
    for (int ks = 0; ks < 4; ++ks) {
        Ah[ks] = *(const short8*)&sDwH[lrow * AP + ks * 32 + kg];
        Al[ks] = *(const short8*)&sDwL[lrow * AP + ks * 32 + kg];
    }

    // per-wave Z: az[j] = Z[(lane>>4)*4+j] (all cols identical)
    short8 ones;
    #pragma unroll
    for (int jj = 0; jj < 8; ++jj) ones[jj] = (short)0x3F80;   // bf16 1.0
    f32x4 az = {0.0f, 0.0f, 0.0f, 0.0f};
    #pragma unroll
    for (int ks = 0; ks < 4; ++ks) {
        az = __builtin_amdgcn_mfma_f32_16x16x32_bf16(Ah[ks], ones, az, 0, 0, 0);
        az = __builtin_amdgcn_mfma_f32_16x16x32_bf16(Al[ks], ones, az, 0, 0, 0);
    }
    float iz[4];
    #pragma unroll
    for (int j = 0; j < 4; ++j) iz[j] = __builtin_amdgcn_rcpf(az[j]);

    #pragma unroll
    for (int ct = 0; ct < 4; ++ct) {
        short8 bh[4];
        if (wv >= 2 && ct < 2) {
            #pragma unroll
            for (int ks = 0; ks < 4; ++ks) bh[ks] = bc[ct][ks];
        } else {
            #pragma unroll
            for (int ks = 0; ks < 4; ++ks) {
                #pragma unroll
                for (int jj = 0; jj < 8; ++jj) {
                    int k = ks * 32 + kg + jj;
                    float u = (mun4[ct] - (T0f + Hf * (float)k)) * is4[ct];
                    float p = __builtin_amdgcn_exp2f(__builtin_fmaf(-LHALF * u, u, S4[ct]));
                    if (k >= DXN) p = 0.0f;
                    bh[ks][jj] = (short)f2bf(p);
                }
            }
        }
        f32x4 a = {0.0f, 0.0f, 0.0f, 0.0f};
        #pragma unroll
        for (int ks = 0; ks < 4; ++ks) {
            a = __builtin_amdgcn_mfma_f32_16x16x32_bf16(Ah[ks], bh[ks], a, 0, 0, 0);
            a = __builtin_amdgcn_mfma_f32_16x16x32_bf16(Al[ks], bh[ks], a, 0, 0, 0);
        }
        const int col = wv * 64 + ct * 16 + lrow;
        #pragma unroll
        for (int j = 0; j < 4; ++j) {
            int row = b0 + (lane >> 4) * 4 + j;
            if (row < Bn) out[row * NB + col] = a[j] * iz[j];
        }
    }
}

extern "C" void kernel_launch(void* const* d_in, const int* in_sizes, int n_in,
                              void* d_out, int out_size, void* d_ws, size_t ws_size,
                              hipStream_t stream) {
    const float* theta = (const float*)d_in[0];
    const float* mu    = (const float*)d_in[1];
    const float* sigma = (const float*)d_in[2];
    float* outp = (float*)d_out;

    int Bn = in_sizes[0] / TC;                  // 4096
    int grid = (Bn + G - 1) / G;                // 256 blocks -> 1 per CU
    fused_kernel<<<grid, BT, 0, stream>>>(theta, mu, sigma, outp, Bn);
}